// Round 1
// baseline (400.226 us; speedup 1.0000x reference)
//
#include <hip/hip_runtime.h>
#include <hip/hip_bf16.h>

#define N_EXPERTS 8
#define T_TOKENS 32768
#define D 512            // D_IN == D_OUT
#define TILE 128
#define BK 64
#define MAX_MTILES 264   // ceil((32768 + 8*127) / 128)
#define SORT_CAP (MAX_MTILES * TILE)   // 33792

typedef __bf16 bf16x8 __attribute__((ext_vector_type(8)));
typedef float  f32x4  __attribute__((ext_vector_type(4)));

__device__ __forceinline__ unsigned short f2bf(float f) {
    unsigned int u = __float_as_uint(f);
    u += 0x7FFFu + ((u >> 16) & 1u);   // round-to-nearest-even
    return (unsigned short)(u >> 16);
}

// ---- pass 1: per-expert histogram ----
__global__ void hist_kernel(const int* __restrict__ p, int* __restrict__ counts) {
    __shared__ int h[N_EXPERTS];
    int tid = threadIdx.x;
    if (tid < N_EXPERTS) h[tid] = 0;
    __syncthreads();
    for (int t = blockIdx.x * blockDim.x + tid; t < T_TOKENS; t += gridDim.x * blockDim.x)
        atomicAdd(&h[p[t]], 1);
    __syncthreads();
    if (tid < N_EXPERTS) atomicAdd(&counts[tid], h[tid]);
}

// ---- pass 2: padded exclusive prefix (tiny, 1 thread) ----
__global__ void offsets_kernel(const int* __restrict__ counts, int* __restrict__ ps) {
    int acc = 0;
    for (int e = 0; e < N_EXPERTS; e++) {
        ps[e] = acc;
        acc += ((counts[e] + TILE - 1) / TILE) * TILE;  // pad to tile multiple
    }
    ps[N_EXPERTS] = acc;
}

// ---- pass 3: scatter token ids into expert segments ----
__global__ void scatter_kernel(const int* __restrict__ p, const int* __restrict__ ps,
                               int* __restrict__ fill, int* __restrict__ sorted) {
    int t = blockIdx.x * blockDim.x + threadIdx.x;
    if (t >= T_TOKENS) return;
    int e = p[t];
    int pos = ps[e] + atomicAdd(&fill[e], 1);
    sorted[pos] = t;
}

// ---- pass 4: grouped GEMM, 128x128 tile, bf16 MFMA ----
__global__ __launch_bounds__(256) void moe_gemm(
        const float* __restrict__ x, const float* __restrict__ W,
        const float* __restrict__ bias, const int* __restrict__ ps,
        const int* __restrict__ sorted, float* __restrict__ out) {
    __shared__ int s_idx[TILE];
    __shared__ unsigned short sA[TILE][BK + 8];   // +8 bf16 pad: stride 144B = 36 dwords
    __shared__ unsigned short sB[TILE][BK + 8];

    int bm = blockIdx.x, bn = blockIdx.y;
    int row0 = bm * TILE;
    int total = ps[N_EXPERTS];
    if (row0 >= total) return;
    int e = 0;
    while (row0 >= ps[e + 1]) e++;   // uniform, <=8 iters

    int tid = threadIdx.x;
    if (tid < TILE) s_idx[tid] = sorted[row0 + tid];
    __syncthreads();

    const float* Wb = W + (size_t)e * D * D + (size_t)(bn * TILE) * D;

    f32x4 acc[4][4];
#pragma unroll
    for (int i = 0; i < 4; i++)
#pragma unroll
        for (int j = 0; j < 4; j++)
            acc[i][j] = (f32x4){0.f, 0.f, 0.f, 0.f};

    int wave = tid >> 6, lane = tid & 63;
    int wm = (wave >> 1) * 64, wn = (wave & 1) * 64;
    int lrow = lane & 15, lq = lane >> 4;

    for (int kk = 0; kk < D; kk += BK) {
        // stage A (gathered token rows, fp32 -> bf16)
#pragma unroll
        for (int i = 0; i < 8; i++) {
            int flat = tid + i * 256;
            int r = flat >> 4, c = (flat & 15) << 2;
            int tok = s_idx[r];
            float4 v = make_float4(0.f, 0.f, 0.f, 0.f);
            if (tok >= 0) v = *(const float4*)(x + (size_t)tok * D + kk + c);
            ushort4 w4;
            w4.x = f2bf(v.x); w4.y = f2bf(v.y); w4.z = f2bf(v.z); w4.w = f2bf(v.w);
            *(ushort4*)&sA[r][c] = w4;
        }
        // stage B (expert weight tile, fp32 -> bf16)
#pragma unroll
        for (int i = 0; i < 8; i++) {
            int flat = tid + i * 256;
            int r = flat >> 4, c = (flat & 15) << 2;
            float4 v = *(const float4*)(Wb + (size_t)r * D + kk + c);
            ushort4 w4;
            w4.x = f2bf(v.x); w4.y = f2bf(v.y); w4.z = f2bf(v.z); w4.w = f2bf(v.w);
            *(ushort4*)&sB[r][c] = w4;
        }
        __syncthreads();
#pragma unroll
        for (int ks = 0; ks < 2; ks++) {
            bf16x8 af[4], bfr[4];
#pragma unroll
            for (int i = 0; i < 4; i++)
                af[i] = *(const bf16x8*)&sA[wm + 16 * i + lrow][ks * 32 + lq * 8];
#pragma unroll
            for (int j = 0; j < 4; j++)
                bfr[j] = *(const bf16x8*)&sB[wn + 16 * j + lrow][ks * 32 + lq * 8];
#pragma unroll
            for (int i = 0; i < 4; i++)
#pragma unroll
                for (int j = 0; j < 4; j++)
                    acc[i][j] = __builtin_amdgcn_mfma_f32_16x16x32_bf16(
                        af[i], bfr[j], acc[i][j], 0, 0, 0);
        }
        __syncthreads();
    }

    // epilogue: bias add + scatter rows back by token id
    // C/D layout: col = lane&15 (n), row = (lane>>4)*4 + reg (m)
#pragma unroll
    for (int j = 0; j < 4; j++) {
        int ng = bn * TILE + wn + 16 * j + lrow;
        float bv = bias[e * D + ng];
#pragma unroll
        for (int i = 0; i < 4; i++) {
#pragma unroll
            for (int r = 0; r < 4; r++) {
                int mrow = wm + 16 * i + lq * 4 + r;
                int tok = s_idx[mrow];
                if (tok >= 0)
                    out[(size_t)tok * D + ng] = acc[i][j][r] + bv;
            }
        }
    }
}

extern "C" void kernel_launch(void* const* d_in, const int* in_sizes, int n_in,
                              void* d_out, int out_size, void* d_ws, size_t ws_size,
                              hipStream_t stream) {
    const float* x    = (const float*)d_in[0];
    const int*   part = (const int*)d_in[1];
    const float* W    = (const float*)d_in[2];
    const float* b    = (const float*)d_in[3];
    float* out = (float*)d_out;

    int* sorted = (int*)d_ws;               // SORT_CAP ints
    int* counts = sorted + SORT_CAP;        // 8
    int* fill   = counts + N_EXPERTS;       // 8
    int* ps     = fill + N_EXPERTS;         // 9

    hipMemsetAsync(sorted, 0xFF, SORT_CAP * sizeof(int), stream);           // -1 fill
    hipMemsetAsync(counts, 0, (2 * N_EXPERTS + N_EXPERTS + 1) * sizeof(int), stream);

    hist_kernel<<<64, 256, 0, stream>>>(part, counts);
    offsets_kernel<<<1, 1, 0, stream>>>(counts, ps);
    scatter_kernel<<<(T_TOKENS + 255) / 256, 256, 0, stream>>>(part, ps, fill, sorted);

    dim3 grid(MAX_MTILES, D / TILE);
    moe_gemm<<<grid, 256, 0, stream>>>(x, W, b, ps, sorted, out);
}

// Round 2
// 240.051 us; speedup vs baseline: 1.6673x; 1.6673x over previous
//
#include <hip/hip_runtime.h>
#include <hip/hip_bf16.h>

#define N_EXPERTS 8
#define T_TOKENS 32768
#define D 512            // D_IN == D_OUT
#define TILE 128
#define BK 64
#define MAX_MTILES 264   // ceil((32768 + 8*127) / 128)
#define SORT_CAP (MAX_MTILES * TILE)   // 33792

typedef __bf16 bf16x8 __attribute__((ext_vector_type(8)));
typedef float  f32x4  __attribute__((ext_vector_type(4)));

__device__ __forceinline__ unsigned short f2bf(float f) {
    unsigned int u = __float_as_uint(f);
    u += 0x7FFFu + ((u >> 16) & 1u);   // round-to-nearest-even
    return (unsigned short)(u >> 16);
}

// ---- pass 1: per-expert histogram ----
__global__ void hist_kernel(const int* __restrict__ p, int* __restrict__ counts) {
    __shared__ int h[N_EXPERTS];
    int tid = threadIdx.x;
    if (tid < N_EXPERTS) h[tid] = 0;
    __syncthreads();
    for (int t = blockIdx.x * blockDim.x + tid; t < T_TOKENS; t += gridDim.x * blockDim.x)
        atomicAdd(&h[p[t]], 1);
    __syncthreads();
    if (tid < N_EXPERTS) atomicAdd(&counts[tid], h[tid]);
}

// ---- pass 2: padded exclusive prefix (tiny, 1 thread) ----
__global__ void offsets_kernel(const int* __restrict__ counts, int* __restrict__ ps) {
    int acc = 0;
    for (int e = 0; e < N_EXPERTS; e++) {
        ps[e] = acc;
        acc += ((counts[e] + TILE - 1) / TILE) * TILE;  // pad to tile multiple
    }
    ps[N_EXPERTS] = acc;
}

// ---- pass 3: scatter token ids into expert segments ----
// Two-level: LDS-local rank (8 LDS counters) + ONE global atomic per
// expert per block to reserve the block's range. 1024 global atomics
// total vs 32768 same-address ones (which cost 175 us serialized).
__global__ void scatter_kernel(const int* __restrict__ p, const int* __restrict__ ps,
                               int* __restrict__ fill, int* __restrict__ sorted) {
    __shared__ int lcount[N_EXPERTS];
    __shared__ int lbase[N_EXPERTS];
    int tid = threadIdx.x;
    if (tid < N_EXPERTS) lcount[tid] = 0;
    __syncthreads();
    int t = blockIdx.x * blockDim.x + tid;
    int e = 0, lrank = 0;
    if (t < T_TOKENS) {
        e = p[t];
        lrank = atomicAdd(&lcount[e], 1);   // LDS atomic: intra-CU, cheap
    }
    __syncthreads();
    if (tid < N_EXPERTS)
        lbase[tid] = (lcount[tid] > 0) ? atomicAdd(&fill[tid], lcount[tid]) : 0;
    __syncthreads();
    if (t < T_TOKENS)
        sorted[ps[e] + lbase[e] + lrank] = t;
}

// ---- pass 4: grouped GEMM, 128x128 tile, bf16 MFMA ----
__global__ __launch_bounds__(256) void moe_gemm(
        const float* __restrict__ x, const float* __restrict__ W,
        const float* __restrict__ bias, const int* __restrict__ ps,
        const int* __restrict__ sorted, float* __restrict__ out) {
    __shared__ int s_idx[TILE];
    __shared__ unsigned short sA[TILE][BK + 8];   // +8 bf16 pad: stride 144B = 36 dwords
    __shared__ unsigned short sB[TILE][BK + 8];

    int bm = blockIdx.x, bn = blockIdx.y;
    int row0 = bm * TILE;
    int total = ps[N_EXPERTS];
    if (row0 >= total) return;
    int e = 0;
    while (row0 >= ps[e + 1]) e++;   // uniform, <=8 iters

    int tid = threadIdx.x;
    if (tid < TILE) s_idx[tid] = sorted[row0 + tid];
    __syncthreads();

    const float* Wb = W + (size_t)e * D * D + (size_t)(bn * TILE) * D;

    f32x4 acc[4][4];
#pragma unroll
    for (int i = 0; i < 4; i++)
#pragma unroll
        for (int j = 0; j < 4; j++)
            acc[i][j] = (f32x4){0.f, 0.f, 0.f, 0.f};

    int wave = tid >> 6, lane = tid & 63;
    int wm = (wave >> 1) * 64, wn = (wave & 1) * 64;
    int lrow = lane & 15, lq = lane >> 4;

    for (int kk = 0; kk < D; kk += BK) {
        // stage A (gathered token rows, fp32 -> bf16)
#pragma unroll
        for (int i = 0; i < 8; i++) {
            int flat = tid + i * 256;
            int r = flat >> 4, c = (flat & 15) << 2;
            int tok = s_idx[r];
            float4 v = make_float4(0.f, 0.f, 0.f, 0.f);
            if (tok >= 0) v = *(const float4*)(x + (size_t)tok * D + kk + c);
            ushort4 w4;
            w4.x = f2bf(v.x); w4.y = f2bf(v.y); w4.z = f2bf(v.z); w4.w = f2bf(v.w);
            *(ushort4*)&sA[r][c] = w4;
        }
        // stage B (expert weight tile, fp32 -> bf16)
#pragma unroll
        for (int i = 0; i < 8; i++) {
            int flat = tid + i * 256;
            int r = flat >> 4, c = (flat & 15) << 2;
            float4 v = *(const float4*)(Wb + (size_t)r * D + kk + c);
            ushort4 w4;
            w4.x = f2bf(v.x); w4.y = f2bf(v.y); w4.z = f2bf(v.z); w4.w = f2bf(v.w);
            *(ushort4*)&sB[r][c] = w4;
        }
        __syncthreads();
#pragma unroll
        for (int ks = 0; ks < 2; ks++) {
            bf16x8 af[4], bfr[4];
#pragma unroll
            for (int i = 0; i < 4; i++)
                af[i] = *(const bf16x8*)&sA[wm + 16 * i + lrow][ks * 32 + lq * 8];
#pragma unroll
            for (int j = 0; j < 4; j++)
                bfr[j] = *(const bf16x8*)&sB[wn + 16 * j + lrow][ks * 32 + lq * 8];
#pragma unroll
            for (int i = 0; i < 4; i++)
#pragma unroll
                for (int j = 0; j < 4; j++)
                    acc[i][j] = __builtin_amdgcn_mfma_f32_16x16x32_bf16(
                        af[i], bfr[j], acc[i][j], 0, 0, 0);
        }
        __syncthreads();
    }

    // epilogue: bias add + scatter rows back by token id
    // C/D layout: col = lane&15 (n), row = (lane>>4)*4 + reg (m)
#pragma unroll
    for (int j = 0; j < 4; j++) {
        int ng = bn * TILE + wn + 16 * j + lrow;
        float bv = bias[e * D + ng];
#pragma unroll
        for (int i = 0; i < 4; i++) {
#pragma unroll
            for (int r = 0; r < 4; r++) {
                int mrow = wm + 16 * i + lq * 4 + r;
                int tok = s_idx[mrow];
                if (tok >= 0)
                    out[(size_t)tok * D + ng] = acc[i][j][r] + bv;
            }
        }
    }
}

extern "C" void kernel_launch(void* const* d_in, const int* in_sizes, int n_in,
                              void* d_out, int out_size, void* d_ws, size_t ws_size,
                              hipStream_t stream) {
    const float* x    = (const float*)d_in[0];
    const int*   part = (const int*)d_in[1];
    const float* W    = (const float*)d_in[2];
    const float* b    = (const float*)d_in[3];
    float* out = (float*)d_out;

    int* sorted = (int*)d_ws;               // SORT_CAP ints
    int* counts = sorted + SORT_CAP;        // 8
    int* fill   = counts + N_EXPERTS;       // 8
    int* ps     = fill + N_EXPERTS;         // 9

    hipMemsetAsync(sorted, 0xFF, SORT_CAP * sizeof(int), stream);           // -1 fill
    hipMemsetAsync(counts, 0, (2 * N_EXPERTS + N_EXPERTS + 1) * sizeof(int), stream);

    hist_kernel<<<64, 256, 0, stream>>>(part, counts);
    offsets_kernel<<<1, 1, 0, stream>>>(counts, ps);
    scatter_kernel<<<(T_TOKENS + 255) / 256, 256, 0, stream>>>(part, ps, fill, sorted);

    dim3 grid(MAX_MTILES, D / TILE);
    moe_gemm<<<grid, 256, 0, stream>>>(x, W, b, ps, sorted, out);
}

// Round 3
// 187.913 us; speedup vs baseline: 2.1298x; 1.2775x over previous
//
#include <hip/hip_runtime.h>
#include <hip/hip_bf16.h>

#define N_EXPERTS 8
#define T_TOKENS 32768
#define D 512            // D_IN == D_OUT
#define TILE 128
#define BK 64
#define MAX_MTILES 264   // ceil((32768 + 8*127) / 128)
#define SORT_CAP (MAX_MTILES * TILE)   // 33792

typedef __bf16 bf16x8 __attribute__((ext_vector_type(8)));
typedef float  f32x4  __attribute__((ext_vector_type(4)));
typedef unsigned short u16x8 __attribute__((ext_vector_type(8)));

__device__ __forceinline__ unsigned short f2bf(float f) {
    unsigned int u = __float_as_uint(f);
    u += 0x7FFFu + ((u >> 16) & 1u);   // round-to-nearest-even
    return (unsigned short)(u >> 16);
}

__device__ __forceinline__ void gl2lds16(const void* g, void* l) {
    // async global->LDS, 16B/lane; LDS dest = wave-uniform base + lane*16
    __builtin_amdgcn_global_load_lds(
        (const __attribute__((address_space(1))) void*)g,
        (__attribute__((address_space(3))) void*)l, 16, 0, 0);
}

// ---- pass 1: per-expert histogram ----
__global__ void hist_kernel(const int* __restrict__ p, int* __restrict__ counts) {
    __shared__ int h[N_EXPERTS];
    int tid = threadIdx.x;
    if (tid < N_EXPERTS) h[tid] = 0;
    __syncthreads();
    for (int t = blockIdx.x * blockDim.x + tid; t < T_TOKENS; t += gridDim.x * blockDim.x)
        atomicAdd(&h[p[t]], 1);
    __syncthreads();
    if (tid < N_EXPERTS) atomicAdd(&counts[tid], h[tid]);
}

// ---- pass 2: padded exclusive prefix ----
__global__ void offsets_kernel(const int* __restrict__ counts, int* __restrict__ ps) {
    int acc = 0;
    for (int e = 0; e < N_EXPERTS; e++) {
        ps[e] = acc;
        acc += ((counts[e] + TILE - 1) / TILE) * TILE;
    }
    ps[N_EXPERTS] = acc;
}

// ---- pass 3: scatter token ids (two-level, low-contention) ----
__global__ void scatter_kernel(const int* __restrict__ p, const int* __restrict__ ps,
                               int* __restrict__ fill, int* __restrict__ sorted) {
    __shared__ int lcount[N_EXPERTS];
    __shared__ int lbase[N_EXPERTS];
    int tid = threadIdx.x;
    if (tid < N_EXPERTS) lcount[tid] = 0;
    __syncthreads();
    int t = blockIdx.x * blockDim.x + tid;
    int e = 0, lrank = 0;
    if (t < T_TOKENS) {
        e = p[t];
        lrank = atomicAdd(&lcount[e], 1);
    }
    __syncthreads();
    if (tid < N_EXPERTS)
        lbase[tid] = (lcount[tid] > 0) ? atomicAdd(&fill[tid], lcount[tid]) : 0;
    __syncthreads();
    if (t < T_TOKENS)
        sorted[ps[e] + lbase[e] + lrank] = t;
}

// ---- pass 3b: gather x rows into sorted order, fp32 -> bf16 ----
// one wave per row; lane reads 32B (8 floats), writes 16B bf16
__global__ __launch_bounds__(256) void gather_convert_x(
        const float* __restrict__ x, const int* __restrict__ sorted,
        const int* __restrict__ ps, unsigned short* __restrict__ xs) {
    int row = blockIdx.x * 4 + (threadIdx.x >> 6);
    if (row >= ps[N_EXPERTS]) return;
    int lane = threadIdx.x & 63;
    int tok = sorted[row];
    u16x8 o;
    if (tok >= 0) {
        const float4* src = (const float4*)(x + (size_t)tok * D + lane * 8);
        float4 a = src[0], b = src[1];
        o[0] = f2bf(a.x); o[1] = f2bf(a.y); o[2] = f2bf(a.z); o[3] = f2bf(a.w);
        o[4] = f2bf(b.x); o[5] = f2bf(b.y); o[6] = f2bf(b.z); o[7] = f2bf(b.w);
    } else {
        o = (u16x8)0;   // pad rows: zeros (MFMA'd but discarded)
    }
    *(u16x8*)&xs[(size_t)row * D + lane * 8] = o;
}

// ---- pass 3c: convert W fp32 -> bf16 ----
__global__ __launch_bounds__(256) void convert_w(
        const float* __restrict__ W, unsigned short* __restrict__ Wb) {
    size_t i = (size_t)(blockIdx.x * 256 + threadIdx.x) * 8;   // 8 floats/thread
    const float4* s = (const float4*)(W + i);
    float4 a = s[0], b = s[1];
    u16x8 o;
    o[0] = f2bf(a.x); o[1] = f2bf(a.y); o[2] = f2bf(a.z); o[3] = f2bf(a.w);
    o[4] = f2bf(b.x); o[5] = f2bf(b.y); o[6] = f2bf(b.z); o[7] = f2bf(b.w);
    *(u16x8*)&Wb[i] = o;
}

// ---- pass 4 (fast): grouped GEMM, bf16 inputs, global_load_lds staging ----
// LDS image is XOR-swizzled on the GLOBAL side: LDS slot (row, cb) holds
// global 16B-block (cb ^ (row&7)) -> fragment ds_read_b128 hits all 32 banks.
__global__ __launch_bounds__(256) void moe_gemm_bf16(
        const unsigned short* __restrict__ xs, const unsigned short* __restrict__ Wb,
        const float* __restrict__ bias, const int* __restrict__ ps,
        const int* __restrict__ sorted, float* __restrict__ out) {
    __shared__ int s_idx[TILE];
    __shared__ unsigned short sA[TILE * BK];   // 16 KB, unpadded (global_load_lds)
    __shared__ unsigned short sB[TILE * BK];   // 16 KB

    int bn = blockIdx.x, bm = blockIdx.y;      // bn fastest: n-tiles of one m-tile adjacent
    int row0 = bm * TILE;
    int total = ps[N_EXPERTS];
    if (row0 >= total) return;
    int e = 0;
    while (row0 >= ps[e + 1]) e++;

    int tid = threadIdx.x;
    if (tid < TILE) s_idx[tid] = sorted[row0 + tid];

    int wave = tid >> 6, lane = tid & 63;
    int wm = (wave >> 1) * 64, wn = (wave & 1) * 64;
    int lrow = lane & 15, lq = lane >> 4;

    // staging geometry: wave handles rows [wave*32, wave*32+32), 4 instrs x 8 rows
    int srow = lane >> 3;                 // sub-row within 8-row group
    int swz = (lane & 7) ^ srow;          // global 16B-block index (XOR swizzle)
    const unsigned short* gA = xs + (size_t)(row0 + wave * 32 + srow) * D + swz * 8;
    const unsigned short* gB = Wb + (size_t)e * D * D
                             + (size_t)(bn * TILE + wave * 32 + srow) * D + swz * 8;
    unsigned short* lA = sA + (wave * 32) * BK;   // + t*8*BK per instr
    unsigned short* lB = sB + (wave * 32) * BK;

    f32x4 acc[4][4];
#pragma unroll
    for (int i = 0; i < 4; i++)
#pragma unroll
        for (int j = 0; j < 4; j++)
            acc[i][j] = (f32x4){0.f, 0.f, 0.f, 0.f};

    for (int kk = 0; kk < D; kk += BK) {
        __syncthreads();   // prev iter's ds_reads done before overwriting LDS
#pragma unroll
        for (int t = 0; t < 4; t++) {
            gl2lds16(gA + (size_t)(t * 8) * D + kk, lA + t * 8 * BK);
            gl2lds16(gB + (size_t)(t * 8) * D + kk, lB + t * 8 * BK);
        }
        __syncthreads();   // drain DMA (vmcnt0) + all waves see LDS
#pragma unroll
        for (int ks = 0; ks < 2; ks++) {
            bf16x8 af[4], bfr[4];
#pragma unroll
            for (int i = 0; i < 4; i++) {
                int row = wm + 16 * i + lrow;
                int cb = (ks * 4 + lq) ^ (lrow & 7);
                af[i] = *(const bf16x8*)&sA[row * BK + cb * 8];
            }
#pragma unroll
            for (int j = 0; j < 4; j++) {
                int row = wn + 16 * j + lrow;
                int cb = (ks * 4 + lq) ^ (lrow & 7);
                bfr[j] = *(const bf16x8*)&sB[row * BK + cb * 8];
            }
#pragma unroll
            for (int i = 0; i < 4; i++)
#pragma unroll
                for (int j = 0; j < 4; j++)
                    acc[i][j] = __builtin_amdgcn_mfma_f32_16x16x32_bf16(
                        af[i], bfr[j], acc[i][j], 0, 0, 0);
        }
    }

    // epilogue: bias + scatter rows back by token id
    // C/D layout: col = lane&15 (n), row = (lane>>4)*4 + reg (m)
#pragma unroll
    for (int j = 0; j < 4; j++) {
        int ng = bn * TILE + wn + 16 * j + lrow;
        float bv = bias[e * D + ng];
#pragma unroll
        for (int i = 0; i < 4; i++) {
#pragma unroll
            for (int r = 0; r < 4; r++) {
                int mrow = wm + 16 * i + lq * 4 + r;
                int tok = s_idx[mrow];
                if (tok >= 0)
                    out[(size_t)tok * D + ng] = acc[i][j][r] + bv;
            }
        }
    }
}

// ---- pass 4 (fallback, small ws): fp32-load GEMM from round 2 ----
__global__ __launch_bounds__(256) void moe_gemm_f32(
        const float* __restrict__ x, const float* __restrict__ W,
        const float* __restrict__ bias, const int* __restrict__ ps,
        const int* __restrict__ sorted, float* __restrict__ out) {
    __shared__ int s_idx[TILE];
    __shared__ unsigned short sA[TILE][BK + 8];
    __shared__ unsigned short sB[TILE][BK + 8];

    int bm = blockIdx.x, bn = blockIdx.y;
    int row0 = bm * TILE;
    int total = ps[N_EXPERTS];
    if (row0 >= total) return;
    int e = 0;
    while (row0 >= ps[e + 1]) e++;

    int tid = threadIdx.x;
    if (tid < TILE) s_idx[tid] = sorted[row0 + tid];
    __syncthreads();

    const float* Wb = W + (size_t)e * D * D + (size_t)(bn * TILE) * D;

    f32x4 acc[4][4];
#pragma unroll
    for (int i = 0; i < 4; i++)
#pragma unroll
        for (int j = 0; j < 4; j++)
            acc[i][j] = (f32x4){0.f, 0.f, 0.f, 0.f};

    int wave = tid >> 6, lane = tid & 63;
    int wm = (wave >> 1) * 64, wn = (wave & 1) * 64;
    int lrow = lane & 15, lq = lane >> 4;

    for (int kk = 0; kk < D; kk += BK) {
#pragma unroll
        for (int i = 0; i < 8; i++) {
            int flat = tid + i * 256;
            int r = flat >> 4, c = (flat & 15) << 2;
            int tok = s_idx[r];
            float4 v = make_float4(0.f, 0.f, 0.f, 0.f);
            if (tok >= 0) v = *(const float4*)(x + (size_t)tok * D + kk + c);
            ushort4 w4;
            w4.x = f2bf(v.x); w4.y = f2bf(v.y); w4.z = f2bf(v.z); w4.w = f2bf(v.w);
            *(ushort4*)&sA[r][c] = w4;
        }
#pragma unroll
        for (int i = 0; i < 8; i++) {
            int flat = tid + i * 256;
            int r = flat >> 4, c = (flat & 15) << 2;
            float4 v = *(const float4*)(Wb + (size_t)r * D + kk + c);
            ushort4 w4;
            w4.x = f2bf(v.x); w4.y = f2bf(v.y); w4.z = f2bf(v.z); w4.w = f2bf(v.w);
            *(ushort4*)&sB[r][c] = w4;
        }
        __syncthreads();
#pragma unroll
        for (int ks = 0; ks < 2; ks++) {
            bf16x8 af[4], bfr[4];
#pragma unroll
            for (int i = 0; i < 4; i++)
                af[i] = *(const bf16x8*)&sA[wm + 16 * i + lrow][ks * 32 + lq * 8];
#pragma unroll
            for (int j = 0; j < 4; j++)
                bfr[j] = *(const bf16x8*)&sB[wn + 16 * j + lrow][ks * 32 + lq * 8];
#pragma unroll
            for (int i = 0; i < 4; i++)
#pragma unroll
                for (int j = 0; j < 4; j++)
                    acc[i][j] = __builtin_amdgcn_mfma_f32_16x16x32_bf16(
                        af[i], bfr[j], acc[i][j], 0, 0, 0);
        }
        __syncthreads();
    }

#pragma unroll
    for (int j = 0; j < 4; j++) {
        int ng = bn * TILE + wn + 16 * j + lrow;
        float bv = bias[e * D + ng];
#pragma unroll
        for (int i = 0; i < 4; i++) {
#pragma unroll
            for (int r = 0; r < 4; r++) {
                int mrow = wm + 16 * i + lq * 4 + r;
                int tok = s_idx[mrow];
                if (tok >= 0)
                    out[(size_t)tok * D + ng] = acc[i][j][r] + bv;
            }
        }
    }
}

extern "C" void kernel_launch(void* const* d_in, const int* in_sizes, int n_in,
                              void* d_out, int out_size, void* d_ws, size_t ws_size,
                              hipStream_t stream) {
    const float* x    = (const float*)d_in[0];
    const int*   part = (const int*)d_in[1];
    const float* W    = (const float*)d_in[2];
    const float* b    = (const float*)d_in[3];
    float* out = (float*)d_out;

    const size_t xs_elems = (size_t)SORT_CAP * D;        // bf16
    const size_t wb_elems = (size_t)N_EXPERTS * D * D;   // bf16
    const size_t fast_bytes = (xs_elems + wb_elems) * 2 + SORT_CAP * 4 + 32 * 4;

    if (ws_size >= fast_bytes) {
        unsigned short* xs = (unsigned short*)d_ws;
        unsigned short* Wb = xs + xs_elems;
        int* sorted = (int*)(Wb + wb_elems);
        int* counts = sorted + SORT_CAP;
        int* fill   = counts + N_EXPERTS;
        int* ps     = fill + N_EXPERTS;

        hipMemsetAsync(sorted, 0xFF, SORT_CAP * sizeof(int), stream);
        hipMemsetAsync(counts, 0, (2 * N_EXPERTS + N_EXPERTS + 1) * sizeof(int), stream);

        hist_kernel<<<64, 256, 0, stream>>>(part, counts);
        offsets_kernel<<<1, 1, 0, stream>>>(counts, ps);
        scatter_kernel<<<(T_TOKENS + 255) / 256, 256, 0, stream>>>(part, ps, fill, sorted);
        gather_convert_x<<<SORT_CAP / 4, 256, 0, stream>>>(x, sorted, ps, xs);
        convert_w<<<(int)(wb_elems / 8 / 256), 256, 0, stream>>>(W, Wb);

        dim3 grid(D / TILE, MAX_MTILES);
        moe_gemm_bf16<<<grid, 256, 0, stream>>>(xs, Wb, b, ps, sorted, out);
    } else {
        int* sorted = (int*)d_ws;
        int* counts = sorted + SORT_CAP;
        int* fill   = counts + N_EXPERTS;
        int* ps     = fill + N_EXPERTS;

        hipMemsetAsync(sorted, 0xFF, SORT_CAP * sizeof(int), stream);
        hipMemsetAsync(counts, 0, (2 * N_EXPERTS + N_EXPERTS + 1) * sizeof(int), stream);

        hist_kernel<<<64, 256, 0, stream>>>(part, counts);
        offsets_kernel<<<1, 1, 0, stream>>>(counts, ps);
        scatter_kernel<<<(T_TOKENS + 255) / 256, 256, 0, stream>>>(part, ps, fill, sorted);

        dim3 grid(MAX_MTILES, D / TILE);
        moe_gemm_f32<<<grid, 256, 0, stream>>>(x, W, b, ps, sorted, out);
    }
}